// Round 6
// baseline (419.112 us; speedup 1.0000x reference)
//
#include <hip/hip_runtime.h>

#define NPIX 9216
#define IMH 96
#define IMW 96
#define NC 21
#define NCH 22          // 21 classes + norm channel
#define CP 24           // pixel-major channel pad
#define NMON 126        // monomials of degree <=4 in 5 vars
#define RAD 15
#define NITER 5
#define MG 11           // monomials per stage1 block
#define NMG 12          // ceil(126/11)
#define LDSS 260        // stage1 LDS pitch (float4-aligned, bank-spread)
#define MCPY 8          // M atomic-spread copies
#define MSZ 3024        // one M copy: 126 rows x 24 (padded)
#define MBUF (MCPY * MSZ)   // one M buffer (8 copies)
#define NTH 384         // k2row threads (6 waves)

// spatial taps exp(-d^2/18), sigma=3
__constant__ float GW[16] = {
    1.0f, 0.945959f, 0.800737f, 0.606531f, 0.411112f, 0.249352f,
    0.135335f, 0.0657285f, 0.0285655f, 0.0111090f, 0.00386592f,
    0.00120386f, 0.000335463f, 8.36523e-05f, 1.86640e-05f, 3.72665e-06f};

// near-minimax deg-4 poly for exp(t) on [0, 1.0384] (all coeffs > 0)
__constant__ float d_bk[5] = {1.000000f, 0.998959f, 0.509936f, 0.139441f, 0.070024f};

// ---- P: unary conv + softmax + features + phi + zero all M ----
__global__ __launch_bounds__(64) void prep_kernel(
    const float* __restrict__ img, const float* __restrict__ net_w,
    const float* __restrict__ net_b,
    float* __restrict__ u_pm, float* __restrict__ s_pm, float* __restrict__ s_cm,
    float* __restrict__ phi, float* __restrict__ Mall)
{
    __shared__ float wsh[567], bsh[21];
    __shared__ float sg_sh[NMON];
    const int tid = threadIdx.x;
    for (int i = tid; i < 567; i += 64) wsh[i] = net_w[i];
    if (tid < 21) bsh[tid] = net_b[tid];
    for (int m = tid; m < NMON; m += 64) {
        int e1 = 0, e2 = 0, e3 = 0, e4 = 0, e5 = 0, cnt = 0;
        bool done = false;
        for (int a = 0; a <= 4 && !done; a++)
            for (int b2 = 0; b2 <= 4 - a && !done; b2++)
                for (int c = 0; c <= 4 - a - b2 && !done; c++)
                    for (int d = 0; d <= 4 - a - b2 - c && !done; d++) {
                        const int rem = 4 - a - b2 - c - d;
                        if (m - cnt <= rem) {
                            e1 = a; e2 = b2; e3 = c; e4 = d; e5 = m - cnt; done = true;
                        } else cnt += rem + 1;
                    }
        const float fact[5] = {1.f, 1.f, 2.f, 6.f, 24.f};
        const int k = e1 + e2 + e3 + e4 + e5;
        sg_sh[m] = sqrtf(d_bk[k] * fact[k] /
                         (fact[e1] * fact[e2] * fact[e3] * fact[e4] * fact[e5]));
    }
    __syncthreads();

    const int px = blockIdx.x * 64 + tid;
    const int i = px / IMW, j = px % IMW;
    for (int idx = px; idx < 3 * MBUF; idx += NPIX) Mall[idx] = 0.f;

    float acc[NC];
    #pragma unroll
    for (int o = 0; o < NC; o++) acc[o] = bsh[o];
    for (int ci = 0; ci < 3; ci++)
        for (int ky = 0; ky < 3; ky++)
            for (int kx = 0; kx < 3; kx++) {
                const int ii = i + ky - 1, jj = j + kx - 1;
                float v = 0.f;
                if (ii >= 0 && ii < IMH && jj >= 0 && jj < IMW)
                    v = img[(ci * IMH + ii) * IMW + jj];
                #pragma unroll
                for (int o = 0; o < NC; o++)
                    acc[o] = fmaf(v, wsh[(ci * 3 + ky) * 3 + kx + o * 27], acc[o]);
            }
    {
        float4* up = (float4*)(u_pm + (size_t)px * CP);
        up[0] = make_float4(acc[0], acc[1], acc[2], acc[3]);
        up[1] = make_float4(acc[4], acc[5], acc[6], acc[7]);
        up[2] = make_float4(acc[8], acc[9], acc[10], acc[11]);
        up[3] = make_float4(acc[12], acc[13], acc[14], acc[15]);
        up[4] = make_float4(acc[16], acc[17], acc[18], acc[19]);
        up[5] = make_float4(acc[20], 0.f, 0.f, 0.f);
    }
    float mx = acc[0];
    #pragma unroll
    for (int o = 1; o < NC; o++) mx = fmaxf(mx, acc[o]);
    float sum = 0.f;
    #pragma unroll
    for (int o = 0; o < NC; o++) { acc[o] = __expf(acc[o] - mx); sum += acc[o]; }
    const float inv = 1.f / sum;
    #pragma unroll
    for (int o = 0; o < NC; o++) acc[o] *= inv;
    {
        float4* sp = (float4*)(s_pm + (size_t)px * CP);
        sp[0] = make_float4(acc[0], acc[1], acc[2], acc[3]);
        sp[1] = make_float4(acc[4], acc[5], acc[6], acc[7]);
        sp[2] = make_float4(acc[8], acc[9], acc[10], acc[11]);
        sp[3] = make_float4(acc[12], acc[13], acc[14], acc[15]);
        sp[4] = make_float4(acc[16], acc[17], acc[18], acc[19]);
        sp[5] = make_float4(acc[20], 1.f, 0.f, 0.f);
    }
    #pragma unroll
    for (int o = 0; o < NC; o++) s_cm[(size_t)o * NPIX + px] = acc[o];
    s_cm[(size_t)21 * NPIX + px] = 1.f;

    const float fv[5] = {(float)j * (1.0f / 160.0f), (float)i * (1.0f / 160.0f),
                         img[0 * NPIX + px] * (1.0f / 3.0f),
                         img[1 * NPIX + px] * (1.0f / 3.0f),
                         img[2 * NPIX + px] * (1.0f / 3.0f)};
    const float env = __expf(-0.5f * (fv[0]*fv[0] + fv[1]*fv[1] + fv[2]*fv[2] +
                                      fv[3]*fv[3] + fv[4]*fv[4]));
    {
        int m = 0;
        float p1 = env;
        #pragma unroll
        for (int e1 = 0; e1 <= 4; e1++) {
            float p2 = p1;
            #pragma unroll
            for (int e2 = 0; e2 <= 4 - e1; e2++) {
                float p3 = p2;
                #pragma unroll
                for (int e3 = 0; e3 <= 4 - e1 - e2; e3++) {
                    float p4 = p3;
                    #pragma unroll
                    for (int e4 = 0; e4 <= 4 - e1 - e2 - e3; e4++) {
                        float p5 = p4;
                        #pragma unroll
                        for (int e5 = 0; e5 <= 4 - e1 - e2 - e3 - e4; e5++) {
                            phi[(size_t)m * NPIX + px] = sg_sh[m] * p5;
                            ++m;
                            p5 *= fv[4];
                        }
                        p4 *= fv[3];
                    }
                    p3 *= fv[2];
                }
                p2 *= fv[1];
            }
            p1 *= fv[0];
        }
    }
}

// ---- K1 (once): stage1 GEMM (8-copy atomic M0) || conv-x of s0 ----
__global__ __launch_bounds__(256) void k1_kernel(
    const float* __restrict__ s_pm, const float* __restrict__ s_cm,
    const float* __restrict__ phi, float* __restrict__ sx, float* __restrict__ M0)
{
    __shared__ float smem[(NCH + MG) * LDSS];
    const int bid = blockIdx.x, tid = threadIdx.x;
    if (bid < NMG * 36) {
        const int g = bid / 36, chunk = bid % 36;
        const int m0 = g * MG;
        const int mcnt = (NMON - m0 < MG) ? (NMON - m0) : MG;
        float* s_sh = smem;
        float* p_sh = smem + NCH * LDSS;
        {
            const float4* sp = (const float4*)(s_pm + (size_t)(chunk * 256 + tid) * CP);
            #pragma unroll
            for (int v = 0; v < 6; v++) {
                const float4 t = sp[v];
                const int c = 4 * v;
                if (c < NCH)     s_sh[c * LDSS + tid] = t.x;
                if (c + 1 < NCH) s_sh[(c + 1) * LDSS + tid] = t.y;
                if (c + 2 < NCH) s_sh[(c + 2) * LDSS + tid] = t.z;
                if (c + 3 < NCH) s_sh[(c + 3) * LDSS + tid] = t.w;
            }
        }
        for (int idx = tid; idx < mcnt * 64; idx += 256) {
            const int mm = idx >> 6, p4 = idx & 63;
            const float4 t = *(const float4*)(phi + (size_t)(m0 + mm) * NPIX +
                                              chunk * 256 + p4 * 4);
            *(float4*)(p_sh + mm * LDSS + p4 * 4) = t;
        }
        __syncthreads();
        const int c = tid % NCH, msub = tid / NCH;
        if (msub < mcnt) {
            const float* sr = s_sh + c * LDSS;
            const float* pr = p_sh + msub * LDSS;
            float acc = 0.f;
            for (int p4 = 0; p4 < 64; p4++) {
                const float4 sv = *(const float4*)(sr + p4 * 4);
                const float4 pv = *(const float4*)(pr + p4 * 4);
                acc += pv.x * sv.x + pv.y * sv.y + pv.z * sv.z + pv.w * sv.w;
            }
            atomicAdd(&M0[(bid & 7) * MSZ + (m0 + msub) * CP + c], acc);
        }
    } else {
        const int u2 = bid - NMG * 36;        // [0, 792)
        const int ch = u2 / 36, pc = u2 % 36;
        const int n = pc * 256 + tid, j = n % IMW;
        const float* row = s_cm + (size_t)ch * NPIX + (n - j);
        float a = GW[0] * row[j];
        #pragma unroll
        for (int d = 1; d <= RAD; d++) {
            const float l = (j - d >= 0) ? row[j - d] : 0.f;
            const float r = (j + d < IMW) ? row[j + d] : 0.f;
            a = fmaf(GW[d], l + r, a);
        }
        sx[(size_t)ch * NPIX + n] = a;
    }
}

// ---- K2ROW: one full row per block; conv-y + stage2 + combine + softmax
//      + row-local conv-x(next) + next-M partial GEMM. One dispatch/iter. ----
__global__ __launch_bounds__(NTH) void k2row_kernel(
    const float* __restrict__ sxin, float* __restrict__ sxout,
    const float* __restrict__ phi,
    const float* __restrict__ Mcur, float* __restrict__ Mnext,
    float* __restrict__ Mzero,
    const float* __restrict__ u_pm,
    const float* __restrict__ sp_w, const float* __restrict__ sp_b,
    const float* __restrict__ bl_w, const float* __restrict__ bl_b,
    const float* __restrict__ comp_w, const float* __restrict__ comp_b,
    float* __restrict__ out, int last)
{
    __shared__ float Msh[MSZ];            // [126][24]  12.1 KB
    __shared__ float cy_sh[96 * 25];      // conv-y (+norm)  9.6 KB
    __shared__ float blv_sh[96 * 25];     // stage2, then probs (25-stride copy)
    __shared__ float mp_sh[96 * CP];      // 9.2 KB
    __shared__ float q_sh[96 * CP];       // logits -> probs  9.2 KB
    __shared__ float wsh[1386 + 63];
    const int tid = threadIdx.x;
    const int i0 = blockIdx.x;            // row [0,96)
    const int px0 = i0 * IMW;

    // M = sum of 8 atomic-spread copies (pad cols stay zero)
    for (int idx = tid; idx < MSZ; idx += NTH) {
        float v = 0.f;
        #pragma unroll
        for (int k = 0; k < MCPY; k++) v += Mcur[k * MSZ + idx];
        Msh[idx] = v;
    }
    for (int idx = tid; idx < 441; idx += NTH) {
        wsh[idx] = sp_w[idx]; wsh[441 + idx] = bl_w[idx]; wsh[882 + idx] = comp_w[idx];
    }
    if (tid < 21) {
        wsh[1323 + tid] = sp_b[tid]; wsh[1344 + tid] = bl_b[tid];
        wsh[1365 + tid] = comp_b[tid];
    }
    // zero it+2 M buffer (96*384 = 36864 >= MBUF)
    if (!last) {
        const int idx = i0 * NTH + tid;
        if (idx < MBUF) Mzero[idx] = 0.f;
    }
    // conv-y: 22ch x 96px tasks from sxin (global, prev dispatch)
    for (int task = tid; task < NCH * 96; task += NTH) {
        const int ch = task / 96, p = task - (task / 96) * 96;
        const float* plane = sxin + (size_t)ch * NPIX;
        const int n = px0 + p;
        float a = GW[0] * plane[n];
        #pragma unroll
        for (int d = 1; d <= RAD; d++) {
            const float t = (i0 - d >= 0) ? plane[n - d * IMW] : 0.f;
            const float b = (i0 + d < IMH) ? plane[n + d * IMW] : 0.f;
            a = fmaf(GW[d], t + b, a);
        }
        cy_sh[p * 25 + ch] = a;
    }
    __syncthreads();

    // stage2: thread = (p = tid%96, channel group of 6); phi read from global
    {
        const int cg = tid / 96, p = tid - cg * 96;
        const int c0 = cg * 6;
        float a[6] = {0.f, 0.f, 0.f, 0.f, 0.f, 0.f};
        const float* pcol = phi + px0 + p;
        for (int mm = 0; mm < NMON; mm++) {
            const float ph = pcol[(size_t)mm * NPIX];
            const float* Mr = Msh + mm * CP + c0;
            #pragma unroll
            for (int c = 0; c < 6; c++) a[c] = fmaf(ph, Mr[c], a[c]);
        }
        #pragma unroll
        for (int c = 0; c < 6; c++)
            if (c0 + c < NCH) blv_sh[p * 25 + c0 + c] = a[c];
    }
    __syncthreads();

    // matmul1: mp = sp_b + bl_b + (sp_w@cy)/cy_norm + (bl_w@blv)/blv_norm
    for (int t = tid; t < 96 * NC; t += NTH) {
        const int o = t / 96, p = t - (t / 96) * 96;
        const float* cyr = cy_sh + p * 25;
        const float* blr = blv_sh + p * 25;
        float dS = 0.f, dB = 0.f;
        #pragma unroll
        for (int c = 0; c < NC; c++) {
            dS = fmaf(wsh[o * NC + c], cyr[c], dS);
            dB = fmaf(wsh[441 + o * NC + c], blr[c], dB);
        }
        mp_sh[p * CP + o] = wsh[1323 + o] + wsh[1344 + o] +
                            dS / cyr[21] + dB / blr[21];
    }
    __syncthreads();

    // matmul2: q = u - (comp_w @ mp + comp_b)
    for (int t = tid; t < 96 * NC; t += NTH) {
        const int o = t / 96, p = t - (t / 96) * 96;
        const float* mpr = mp_sh + p * CP;
        float d = wsh[1365 + o];
        #pragma unroll
        for (int c = 0; c < NC; c++) d = fmaf(wsh[882 + o * NC + c], mpr[c], d);
        q_sh[p * CP + o] = u_pm[(size_t)(px0 + p) * CP + o] - d;
    }
    __syncthreads();

    // softmax, thread = pixel; probs into q_sh (24-stride) AND blv_sh (25-stride)
    if (tid < 96) {
        const int p = tid;
        float q[NC];
        #pragma unroll
        for (int o = 0; o < NC; o++) q[o] = q_sh[p * CP + o];
        float mx = q[0];
        #pragma unroll
        for (int o = 1; o < NC; o++) mx = fmaxf(mx, q[o]);
        float sum = 0.f;
        #pragma unroll
        for (int o = 0; o < NC; o++) { q[o] = __expf(q[o] - mx); sum += q[o]; }
        const float inv = 1.f / sum;
        #pragma unroll
        for (int o = 0; o < NC; o++) q[o] *= inv;
        #pragma unroll
        for (int o = 0; o < NC; o++) { q_sh[p * CP + o] = q[o]; blv_sh[p * 25 + o] = q[o]; }
        q_sh[p * CP + 21] = 1.f; q_sh[p * CP + 22] = 0.f; q_sh[p * CP + 23] = 0.f;
        blv_sh[p * 25 + 21] = 1.f;
        if (last)
            #pragma unroll
            for (int o = 0; o < NC; o++) out[(size_t)o * NPIX + px0 + p] = q[o];
    }
    __syncthreads();
    if (last) return;

    // row-local conv-x of the new s -> sxout (next iteration's conv-y input)
    for (int task = tid; task < NCH * 96; task += NTH) {
        const int ch = task / 96, p = task - (task / 96) * 96;
        float a = GW[0] * blv_sh[p * 25 + ch];
        #pragma unroll
        for (int d = 1; d <= RAD; d++) {
            const float l = (p - d >= 0) ? blv_sh[(p - d) * 25 + ch] : 0.f;
            const float r = (p + d < 96) ? blv_sh[(p + d) * 25 + ch] : 0.f;
            a = fmaf(GW[d], l + r, a);
        }
        sxout[(size_t)ch * NPIX + px0 + p] = a;
    }

    // next-M partial: Mnext += phi_row[126][96] @ s_new[96][24-padded]
    {
        float* Md = Mnext + (i0 & 7) * MSZ;
        for (int task = tid; task < 756; task += NTH) {   // 126 m x 6 c-quads
            const int m = task / 6, c0 = (task - (task / 6) * 6) * 4;
            const float* pcol = phi + (size_t)m * NPIX + px0;
            float ax = 0.f, ay = 0.f, az = 0.f, aw = 0.f;
            for (int p = 0; p < 96; p++) {
                const float ph = pcol[p];
                const float4 qv = *(const float4*)(q_sh + p * CP + c0);
                ax = fmaf(ph, qv.x, ax); ay = fmaf(ph, qv.y, ay);
                az = fmaf(ph, qv.z, az); aw = fmaf(ph, qv.w, aw);
            }
            atomicAdd(&Md[m * CP + c0],     ax);
            atomicAdd(&Md[m * CP + c0 + 1], ay);
            if (c0 < 20) {                                // skip pad cols 22,23
                atomicAdd(&Md[m * CP + c0 + 2], az);
                atomicAdd(&Md[m * CP + c0 + 3], aw);
            }
        }
    }
}

extern "C" void kernel_launch(void* const* d_in, const int* in_sizes, int n_in,
                              void* d_out, int out_size, void* d_ws, size_t ws_size,
                              hipStream_t stream) {
    const float* img    = (const float*)d_in[0];
    const float* net_w  = (const float*)d_in[1];
    const float* net_b  = (const float*)d_in[2];
    const float* sp_w   = (const float*)d_in[3];
    const float* sp_b   = (const float*)d_in[4];
    const float* bl_w   = (const float*)d_in[5];
    const float* bl_b   = (const float*)d_in[6];
    const float* comp_w = (const float*)d_in[7];
    const float* comp_b = (const float*)d_in[8];

    float* u_pm = (float*)d_ws;                  // [NPIX][24]
    float* s_pm = u_pm + (size_t)NPIX * CP;      // [NPIX][24]
    float* s_cm = s_pm + (size_t)NPIX * CP;      // [22][NPIX]
    float* sx0  = s_cm + (size_t)NCH * NPIX;     // [22][NPIX] double-buffered
    float* sx1  = sx0 + (size_t)NCH * NPIX;      // [22][NPIX]
    float* phi  = sx1 + (size_t)NCH * NPIX;      // [126][NPIX]
    float* M3   = phi + (size_t)NMON * NPIX;     // [3][8][3024]

    float* out = (float*)d_out;

    prep_kernel<<<dim3(144), dim3(64), 0, stream>>>(
        img, net_w, net_b, u_pm, s_pm, s_cm, phi, M3);
    k1_kernel<<<dim3(NMG * 36 + NCH * 36), dim3(256), 0, stream>>>(
        s_pm, s_cm, phi, sx0, M3);               // M buffer 0 + sx(it0)
    for (int it = 0; it < NITER; it++) {
        float* Mc = M3 + (size_t)(it % 3) * MBUF;
        float* Mn = M3 + (size_t)((it + 1) % 3) * MBUF;
        float* Mz = M3 + (size_t)((it + 2) % 3) * MBUF;
        float* sin  = (it & 1) ? sx1 : sx0;
        float* sout = (it & 1) ? sx0 : sx1;
        k2row_kernel<<<dim3(96), dim3(NTH), 0, stream>>>(
            sin, sout, phi, Mc, Mn, Mz, u_pm,
            sp_w, sp_b, bl_w, bl_b, comp_w, comp_b,
            out, it == NITER - 1 ? 1 : 0);
    }
}

// Round 7
// 218.762 us; speedup vs baseline: 1.9158x; 1.9158x over previous
//
#include <hip/hip_runtime.h>

#define NPIX 9216
#define IMH 96
#define IMW 96
#define NC 21
#define NCH 22          // 21 classes + norm channel
#define CP 24           // pixel-major channel pad
#define NMON 126        // monomials of degree <=4 in 5 vars
#define RAD 15
#define NITER 5
#define MG 11           // monomials per stage1 block
#define NMG 12          // ceil(126/11)
#define LDSS 260        // stage1 LDS pitch (float4-aligned, bank-spread)
#define MPAD 2816       // M buffer stride (>=126*22)

// spatial taps exp(-d^2/18), sigma=3
__constant__ float GW[16] = {
    1.0f, 0.945959f, 0.800737f, 0.606531f, 0.411112f, 0.249352f,
    0.135335f, 0.0657285f, 0.0285655f, 0.0111090f, 0.00386592f,
    0.00120386f, 0.000335463f, 8.36523e-05f, 1.86640e-05f, 3.72665e-06f};

// near-minimax deg-4 poly for exp(t) on [0, 1.0384] (all coeffs > 0)
__constant__ float d_bk[5] = {1.000000f, 0.998959f, 0.509936f, 0.139441f, 0.070024f};

// ---- P: two block roles, one dispatch.
//   blocks [0,36):   conv + softmax + u/s writes + zero M0 (1 thread/pixel)
//   blocks [36,324): phi only -- 32 px/block, 8 threads/pixel; each thread
//                    recomputes the full running-product chain in registers
//                    (~170 VALU) and stores only its 16-monomial window.
//                    1152 + 144 waves total vs round-1's 144: latency hidden.
__global__ __launch_bounds__(256) void prep_kernel(
    const float* __restrict__ img, const float* __restrict__ net_w,
    const float* __restrict__ net_b,
    float* __restrict__ u_pm, float* __restrict__ s_pm, float* __restrict__ s_cm,
    float* __restrict__ phi, float* __restrict__ M0)
{
    __shared__ float wsh[567], bsh[21];
    __shared__ float sg_sh[NMON];
    const int tid = threadIdx.x;
    const int bid = blockIdx.x;

    if (bid < 36) {
        // ---- role A: unary conv + softmax + u/s + zero M0 ----
        for (int i2 = tid; i2 < 567; i2 += 256) wsh[i2] = net_w[i2];
        if (tid < 21) bsh[tid] = net_b[tid];
        __syncthreads();

        const int px = bid * 256 + tid;
        const int i = px / IMW, j = px % IMW;
        if (px < 2772) M0[px] = 0.f;

        float acc[NC];
        #pragma unroll
        for (int o = 0; o < NC; o++) acc[o] = bsh[o];
        for (int ci = 0; ci < 3; ci++)
            for (int ky = 0; ky < 3; ky++)
                for (int kx = 0; kx < 3; kx++) {
                    const int ii = i + ky - 1, jj = j + kx - 1;
                    float v = 0.f;
                    if (ii >= 0 && ii < IMH && jj >= 0 && jj < IMW)
                        v = img[(ci * IMH + ii) * IMW + jj];
                    #pragma unroll
                    for (int o = 0; o < NC; o++)
                        acc[o] = fmaf(v, wsh[(ci * 3 + ky) * 3 + kx + o * 27], acc[o]);
                }
        {   // u then softmax
            float4* up = (float4*)(u_pm + (size_t)px * CP);
            up[0] = make_float4(acc[0], acc[1], acc[2], acc[3]);
            up[1] = make_float4(acc[4], acc[5], acc[6], acc[7]);
            up[2] = make_float4(acc[8], acc[9], acc[10], acc[11]);
            up[3] = make_float4(acc[12], acc[13], acc[14], acc[15]);
            up[4] = make_float4(acc[16], acc[17], acc[18], acc[19]);
            up[5] = make_float4(acc[20], 0.f, 0.f, 0.f);
        }
        float mx = acc[0];
        #pragma unroll
        for (int o = 1; o < NC; o++) mx = fmaxf(mx, acc[o]);
        float sum = 0.f;
        #pragma unroll
        for (int o = 0; o < NC; o++) { acc[o] = __expf(acc[o] - mx); sum += acc[o]; }
        const float inv = 1.f / sum;
        #pragma unroll
        for (int o = 0; o < NC; o++) acc[o] *= inv;
        {
            float4* sp = (float4*)(s_pm + (size_t)px * CP);
            sp[0] = make_float4(acc[0], acc[1], acc[2], acc[3]);
            sp[1] = make_float4(acc[4], acc[5], acc[6], acc[7]);
            sp[2] = make_float4(acc[8], acc[9], acc[10], acc[11]);
            sp[3] = make_float4(acc[12], acc[13], acc[14], acc[15]);
            sp[4] = make_float4(acc[16], acc[17], acc[18], acc[19]);
            sp[5] = make_float4(acc[20], 1.f, 0.f, 0.f);
        }
        #pragma unroll
        for (int o = 0; o < NC; o++) s_cm[(size_t)o * NPIX + px] = acc[o];
        s_cm[(size_t)21 * NPIX + px] = 1.f;
    } else {
        // ---- role B: phi, 8 threads/pixel ----
        for (int m = tid; m < NMON; m += 256) {
            int e1 = 0, e2 = 0, e3 = 0, e4 = 0, e5 = 0, cnt = 0;
            bool done = false;
            for (int a = 0; a <= 4 && !done; a++)
                for (int b2 = 0; b2 <= 4 - a && !done; b2++)
                    for (int c = 0; c <= 4 - a - b2 && !done; c++)
                        for (int d = 0; d <= 4 - a - b2 - c && !done; d++) {
                            const int rem = 4 - a - b2 - c - d;
                            if (m - cnt <= rem) {
                                e1 = a; e2 = b2; e3 = c; e4 = d; e5 = m - cnt;
                                done = true;
                            } else cnt += rem + 1;
                        }
            const float fact[5] = {1.f, 1.f, 2.f, 6.f, 24.f};
            const int k = e1 + e2 + e3 + e4 + e5;
            sg_sh[m] = sqrtf(d_bk[k] * fact[k] /
                             (fact[e1] * fact[e2] * fact[e3] * fact[e4] * fact[e5]));
        }
        __syncthreads();

        const int px = (bid - 36) * 32 + (tid & 31);
        const unsigned c0 = (tid >> 5) * 16;      // this thread's store window
        const int i = px / IMW, j = px % IMW;
        const float fv[5] = {(float)j * (1.0f / 160.0f), (float)i * (1.0f / 160.0f),
                             img[0 * NPIX + px] * (1.0f / 3.0f),
                             img[1 * NPIX + px] * (1.0f / 3.0f),
                             img[2 * NPIX + px] * (1.0f / 3.0f)};
        const float env = __expf(-0.5f * (fv[0]*fv[0] + fv[1]*fv[1] + fv[2]*fv[2] +
                                          fv[3]*fv[3] + fv[4]*fv[4]));
        int m = 0;
        float p1 = env;
        #pragma unroll
        for (int e1 = 0; e1 <= 4; e1++) {
            float p2 = p1;
            #pragma unroll
            for (int e2 = 0; e2 <= 4 - e1; e2++) {
                float p3 = p2;
                #pragma unroll
                for (int e3 = 0; e3 <= 4 - e1 - e2; e3++) {
                    float p4 = p3;
                    #pragma unroll
                    for (int e4 = 0; e4 <= 4 - e1 - e2 - e3; e4++) {
                        float p5 = p4;
                        #pragma unroll
                        for (int e5 = 0; e5 <= 4 - e1 - e2 - e3 - e4; e5++) {
                            if ((unsigned)(m - c0) < 16u)
                                phi[(size_t)m * NPIX + px] = sg_sh[m] * p5;
                            ++m;
                            p5 *= fv[4];
                        }
                        p4 *= fv[3];
                    }
                    p3 *= fv[2];
                }
                p2 *= fv[1];
            }
            p1 *= fv[0];
        }
    }
}

// ---- K1: stage1 GEMM (LDS b128 dot, atomic M) || conv-x ----
__global__ __launch_bounds__(256) void k1_kernel(
    const float* __restrict__ s_pm, const float* __restrict__ s_cm,
    const float* __restrict__ phi, float* __restrict__ sx, float* __restrict__ M)
{
    __shared__ float smem[(NCH + MG) * LDSS];
    const int bid = blockIdx.x, tid = threadIdx.x;
    if (bid < NMG * 36) {
        const int g = bid / 36, chunk = bid % 36;
        const int m0 = g * MG;
        const int mcnt = (NMON - m0 < MG) ? (NMON - m0) : MG;
        float* s_sh = smem;
        float* p_sh = smem + NCH * LDSS;
        {
            const float4* sp = (const float4*)(s_pm + (size_t)(chunk * 256 + tid) * CP);
            #pragma unroll
            for (int v = 0; v < 6; v++) {
                const float4 t = sp[v];
                const int c = 4 * v;
                if (c < NCH)     s_sh[c * LDSS + tid] = t.x;
                if (c + 1 < NCH) s_sh[(c + 1) * LDSS + tid] = t.y;
                if (c + 2 < NCH) s_sh[(c + 2) * LDSS + tid] = t.z;
                if (c + 3 < NCH) s_sh[(c + 3) * LDSS + tid] = t.w;
            }
        }
        for (int idx = tid; idx < mcnt * 64; idx += 256) {
            const int mm = idx >> 6, p4 = idx & 63;
            const float4 t = *(const float4*)(phi + (size_t)(m0 + mm) * NPIX +
                                              chunk * 256 + p4 * 4);
            *(float4*)(p_sh + mm * LDSS + p4 * 4) = t;
        }
        __syncthreads();
        const int c = tid % NCH, msub = tid / NCH;
        if (msub < mcnt) {
            const float* sr = s_sh + c * LDSS;
            const float* pr = p_sh + msub * LDSS;
            float acc = 0.f;
            for (int p4 = 0; p4 < 64; p4++) {
                const float4 sv = *(const float4*)(sr + p4 * 4);
                const float4 pv = *(const float4*)(pr + p4 * 4);
                acc += pv.x * sv.x + pv.y * sv.y + pv.z * sv.z + pv.w * sv.w;
            }
            atomicAdd(&M[(m0 + msub) * NCH + c], acc);
        }
    } else {
        const int u2 = bid - NMG * 36;        // [0, 792)
        const int ch = u2 / 36, pc = u2 % 36;
        const int n = pc * 256 + tid, j = n % IMW;
        const float* row = s_cm + (size_t)ch * NPIX + (n - j);
        float a = GW[0] * row[j];
        #pragma unroll
        for (int d = 1; d <= RAD; d++) {
            const float l = (j - d >= 0) ? row[j - d] : 0.f;
            const float r = (j + d < IMW) ? row[j + d] : 0.f;
            a = fmaf(GW[d], l + r, a);
        }
        sx[(size_t)ch * NPIX + n] = a;
    }
}

// ---- K2: conv-y + stage2 + combine + softmax, 32 px per block ----
__global__ __launch_bounds__(256) void k2_kernel(
    const float* __restrict__ sx, const float* __restrict__ phi,
    const float* __restrict__ M, float* __restrict__ Mnext,
    const float* __restrict__ u_pm,
    const float* __restrict__ sp_w, const float* __restrict__ sp_b,
    const float* __restrict__ bl_w, const float* __restrict__ bl_b,
    const float* __restrict__ comp_w, const float* __restrict__ comp_b,
    float* __restrict__ s_pm, float* __restrict__ s_cm,
    float* __restrict__ out, int write_out)
{
    __shared__ float Msh[NMON * CP];      // 3024
    __shared__ float phi_sh[NMON * 32];   // 4032
    __shared__ float cy_sh[32 * 25];      // conv-y result (+inv slots)
    __shared__ float blv_sh[32 * 25];
    __shared__ float mp_sh[32 * CP];
    __shared__ float q_sh[32 * CP];
    __shared__ float wsh[1386 + 63];
    const int tid = threadIdx.x;
    const int px0 = blockIdx.x * 32;
    const int i0 = px0 / IMW;             // block-uniform row (96 = 3*32)

    for (int idx = tid; idx < NMON * CP; idx += 256) {
        const int mm = idx / CP, c = idx % CP;
        Msh[idx] = (c < NCH) ? M[mm * NCH + c] : 0.f;
    }
    for (int idx = tid; idx < 441; idx += 256) {
        wsh[idx] = sp_w[idx]; wsh[441 + idx] = bl_w[idx]; wsh[882 + idx] = comp_w[idx];
    }
    if (tid < 21) {
        wsh[1323 + tid] = sp_b[tid]; wsh[1344 + tid] = bl_b[tid];
        wsh[1365 + tid] = comp_b[tid];
    }
    if (blockIdx.x < 11) {
        const int idx = blockIdx.x * 256 + tid;
        if (idx < 2772) Mnext[idx] = 0.f;
    }
    // phi tile [126][32]
    for (int idx = tid; idx < NMON * 8; idx += 256) {
        const int m = idx >> 3, g = idx & 7;
        *(float4*)(phi_sh + m * 32 + g * 4) =
            *(const float4*)(phi + (size_t)m * NPIX + px0 + g * 4);
    }
    // conv-y: 24*32 tasks (ch >= 22 idle)
    for (int task = tid; task < 24 * 32; task += 256) {
        const int ch = task >> 5, p = task & 31;
        if (ch < NCH) {
            const int n = px0 + p;
            const float* plane = sx + (size_t)ch * NPIX;
            float a = GW[0] * plane[n];
            #pragma unroll
            for (int d = 1; d <= RAD; d++) {
                const float t = (i0 - d >= 0) ? plane[n - d * IMW] : 0.f;
                const float b = (i0 + d < IMH) ? plane[n + d * IMW] : 0.f;
                a = fmaf(GW[d], t + b, a);
            }
            cy_sh[p * 25 + ch] = a;
        }
    }
    __syncthreads();

    // stage2: thread = (px, 3-channel group)
    {
        const int p = tid & 31, c0 = (tid >> 5) * 3;
        float a0 = 0.f, a1 = 0.f, a2 = 0.f;
        for (int mm = 0; mm < NMON; mm++) {
            const float ph = phi_sh[mm * 32 + p];
            const float* Mr = Msh + mm * CP + c0;
            a0 = fmaf(ph, Mr[0], a0);
            a1 = fmaf(ph, Mr[1], a1);
            a2 = fmaf(ph, Mr[2], a2);
        }
        if (c0 < NCH)     blv_sh[p * 25 + c0] = a0;
        if (c0 + 1 < NCH) blv_sh[p * 25 + c0 + 1] = a1;
        if (c0 + 2 < NCH) blv_sh[p * 25 + c0 + 2] = a2;
    }
    __syncthreads();

    // matmul1: mp = sp_b + bl_b + invS*(sp_w@cy) + invB*(bl_w@blv)
    for (int t = tid; t < 672; t += 256) {
        const int p = t & 31, o = t >> 5;
        const float* cyr = cy_sh + p * 25;
        const float* blr = blv_sh + p * 25;
        float dS = 0.f, dB = 0.f;
        #pragma unroll
        for (int c = 0; c < NC; c++) {
            dS = fmaf(wsh[o * NC + c], cyr[c], dS);
            dB = fmaf(wsh[441 + o * NC + c], blr[c], dB);
        }
        mp_sh[p * CP + o] = wsh[1323 + o] + wsh[1344 + o] +
                            dS / cyr[21] + dB / blr[21];
    }
    __syncthreads();

    // matmul2: q = u - (comp_w @ mp + comp_b)
    for (int t = tid; t < 672; t += 256) {
        const int p = t & 31, o = t >> 5;
        const float* mpr = mp_sh + p * CP;
        float d = wsh[1365 + o];
        #pragma unroll
        for (int c = 0; c < NC; c++) d = fmaf(wsh[882 + o * NC + c], mpr[c], d);
        q_sh[p * CP + o] = u_pm[(size_t)(px0 + p) * CP + o] - d;
    }
    __syncthreads();

    // softmax + writes, thread = pixel
    if (tid < 32) {
        const int n = px0 + tid;
        float q[NC];
        #pragma unroll
        for (int o = 0; o < NC; o++) q[o] = q_sh[tid * CP + o];
        float mx = q[0];
        #pragma unroll
        for (int o = 1; o < NC; o++) mx = fmaxf(mx, q[o]);
        float sum = 0.f;
        #pragma unroll
        for (int o = 0; o < NC; o++) { q[o] = __expf(q[o] - mx); sum += q[o]; }
        const float inv = 1.f / sum;
        #pragma unroll
        for (int o = 0; o < NC; o++) q[o] *= inv;

        float4* sp = (float4*)(s_pm + (size_t)n * CP);
        sp[0] = make_float4(q[0], q[1], q[2], q[3]);
        sp[1] = make_float4(q[4], q[5], q[6], q[7]);
        sp[2] = make_float4(q[8], q[9], q[10], q[11]);
        sp[3] = make_float4(q[12], q[13], q[14], q[15]);
        sp[4] = make_float4(q[16], q[17], q[18], q[19]);
        sp[5] = make_float4(q[20], 1.f, 0.f, 0.f);
        #pragma unroll
        for (int o = 0; o < NC; o++) s_cm[(size_t)o * NPIX + n] = q[o];
        s_cm[(size_t)21 * NPIX + n] = 1.f;
        if (write_out)
            #pragma unroll
            for (int o = 0; o < NC; o++) out[(size_t)o * NPIX + n] = q[o];
    }
}

extern "C" void kernel_launch(void* const* d_in, const int* in_sizes, int n_in,
                              void* d_out, int out_size, void* d_ws, size_t ws_size,
                              hipStream_t stream) {
    const float* img    = (const float*)d_in[0];
    const float* net_w  = (const float*)d_in[1];
    const float* net_b  = (const float*)d_in[2];
    const float* sp_w   = (const float*)d_in[3];
    const float* sp_b   = (const float*)d_in[4];
    const float* bl_w   = (const float*)d_in[5];
    const float* bl_b   = (const float*)d_in[6];
    const float* comp_w = (const float*)d_in[7];
    const float* comp_b = (const float*)d_in[8];

    float* u_pm = (float*)d_ws;                  // [NPIX][24]
    float* s_pm = u_pm + (size_t)NPIX * CP;      // [NPIX][24]
    float* s_cm = s_pm + (size_t)NPIX * CP;      // [22][NPIX]
    float* sx   = s_cm + (size_t)NCH * NPIX;     // [22][NPIX]
    float* phi  = sx + (size_t)NCH * NPIX;       // [126][NPIX]
    float* M    = phi + (size_t)NMON * NPIX;     // [2][MPAD]

    float* out = (float*)d_out;

    prep_kernel<<<dim3(36 + 288), dim3(256), 0, stream>>>(
        img, net_w, net_b, u_pm, s_pm, s_cm, phi, M);
    for (int it = 0; it < NITER; it++) {
        float* Mc = M + (it & 1) * MPAD;
        float* Mn = M + ((it + 1) & 1) * MPAD;
        k1_kernel<<<dim3(NMG * 36 + NCH * 36), dim3(256), 0, stream>>>(
            s_pm, s_cm, phi, sx, Mc);
        k2_kernel<<<dim3(288), dim3(256), 0, stream>>>(
            sx, phi, Mc, Mn, u_pm, sp_w, sp_b, bl_w, bl_b, comp_w, comp_b,
            s_pm, s_cm, out, it == NITER - 1 ? 1 : 0);
    }
}

// Round 8
// 206.919 us; speedup vs baseline: 2.0255x; 1.0572x over previous
//
#include <hip/hip_runtime.h>

#define NPIX 9216
#define IMH 96
#define IMW 96
#define NC 21
#define NCH 22          // 21 classes + norm channel
#define CP 24           // pixel-major channel pad
#define NMON 126        // monomials of degree <=4 in 5 vars
#define RAD 15
#define NITER 5
#define MG 11           // monomials per stage1 block
#define NMG 12          // ceil(126/11)
#define LDSS 260        // stage1 LDS pitch (float4-aligned, bank-spread)
#define MPAD 2816       // M buffer stride (>=126*22)
#define K2PX 16         // k2 pixels per block (576 blocks = 2.25/CU)

// spatial taps exp(-d^2/18), sigma=3
__constant__ float GW[16] = {
    1.0f, 0.945959f, 0.800737f, 0.606531f, 0.411112f, 0.249352f,
    0.135335f, 0.0657285f, 0.0285655f, 0.0111090f, 0.00386592f,
    0.00120386f, 0.000335463f, 8.36523e-05f, 1.86640e-05f, 3.72665e-06f};

// near-minimax deg-4 poly for exp(t) on [0, 1.0384] (all coeffs > 0)
__constant__ float d_bk[5] = {1.000000f, 0.998959f, 0.509936f, 0.139441f, 0.070024f};

// ---- P: two block roles, one dispatch (round-7, proven) ----
__global__ __launch_bounds__(256) void prep_kernel(
    const float* __restrict__ img, const float* __restrict__ net_w,
    const float* __restrict__ net_b,
    float* __restrict__ u_pm, float* __restrict__ s_pm, float* __restrict__ s_cm,
    float* __restrict__ phi, float* __restrict__ M0)
{
    __shared__ float wsh[567], bsh[21];
    __shared__ float sg_sh[NMON];
    const int tid = threadIdx.x;
    const int bid = blockIdx.x;

    if (bid < 36) {
        // ---- role A: unary conv + softmax + u/s + zero M0 ----
        for (int i2 = tid; i2 < 567; i2 += 256) wsh[i2] = net_w[i2];
        if (tid < 21) bsh[tid] = net_b[tid];
        __syncthreads();

        const int px = bid * 256 + tid;
        const int i = px / IMW, j = px % IMW;
        if (px < 2772) M0[px] = 0.f;

        float acc[NC];
        #pragma unroll
        for (int o = 0; o < NC; o++) acc[o] = bsh[o];
        for (int ci = 0; ci < 3; ci++)
            for (int ky = 0; ky < 3; ky++)
                for (int kx = 0; kx < 3; kx++) {
                    const int ii = i + ky - 1, jj = j + kx - 1;
                    float v = 0.f;
                    if (ii >= 0 && ii < IMH && jj >= 0 && jj < IMW)
                        v = img[(ci * IMH + ii) * IMW + jj];
                    #pragma unroll
                    for (int o = 0; o < NC; o++)
                        acc[o] = fmaf(v, wsh[(ci * 3 + ky) * 3 + kx + o * 27], acc[o]);
                }
        {   // u then softmax
            float4* up = (float4*)(u_pm + (size_t)px * CP);
            up[0] = make_float4(acc[0], acc[1], acc[2], acc[3]);
            up[1] = make_float4(acc[4], acc[5], acc[6], acc[7]);
            up[2] = make_float4(acc[8], acc[9], acc[10], acc[11]);
            up[3] = make_float4(acc[12], acc[13], acc[14], acc[15]);
            up[4] = make_float4(acc[16], acc[17], acc[18], acc[19]);
            up[5] = make_float4(acc[20], 0.f, 0.f, 0.f);
        }
        float mx = acc[0];
        #pragma unroll
        for (int o = 1; o < NC; o++) mx = fmaxf(mx, acc[o]);
        float sum = 0.f;
        #pragma unroll
        for (int o = 0; o < NC; o++) { acc[o] = __expf(acc[o] - mx); sum += acc[o]; }
        const float inv = 1.f / sum;
        #pragma unroll
        for (int o = 0; o < NC; o++) acc[o] *= inv;
        {
            float4* sp = (float4*)(s_pm + (size_t)px * CP);
            sp[0] = make_float4(acc[0], acc[1], acc[2], acc[3]);
            sp[1] = make_float4(acc[4], acc[5], acc[6], acc[7]);
            sp[2] = make_float4(acc[8], acc[9], acc[10], acc[11]);
            sp[3] = make_float4(acc[12], acc[13], acc[14], acc[15]);
            sp[4] = make_float4(acc[16], acc[17], acc[18], acc[19]);
            sp[5] = make_float4(acc[20], 1.f, 0.f, 0.f);
        }
        #pragma unroll
        for (int o = 0; o < NC; o++) s_cm[(size_t)o * NPIX + px] = acc[o];
        s_cm[(size_t)21 * NPIX + px] = 1.f;
    } else {
        // ---- role B: phi, 8 threads/pixel, 16-monomial store window each ----
        for (int m = tid; m < NMON; m += 256) {
            int e1 = 0, e2 = 0, e3 = 0, e4 = 0, e5 = 0, cnt = 0;
            bool done = false;
            for (int a = 0; a <= 4 && !done; a++)
                for (int b2 = 0; b2 <= 4 - a && !done; b2++)
                    for (int c = 0; c <= 4 - a - b2 && !done; c++)
                        for (int d = 0; d <= 4 - a - b2 - c && !done; d++) {
                            const int rem = 4 - a - b2 - c - d;
                            if (m - cnt <= rem) {
                                e1 = a; e2 = b2; e3 = c; e4 = d; e5 = m - cnt;
                                done = true;
                            } else cnt += rem + 1;
                        }
            const float fact[5] = {1.f, 1.f, 2.f, 6.f, 24.f};
            const int k = e1 + e2 + e3 + e4 + e5;
            sg_sh[m] = sqrtf(d_bk[k] * fact[k] /
                             (fact[e1] * fact[e2] * fact[e3] * fact[e4] * fact[e5]));
        }
        __syncthreads();

        const int px = (bid - 36) * 32 + (tid & 31);
        const unsigned c0 = (tid >> 5) * 16;      // this thread's store window
        const int i = px / IMW, j = px % IMW;
        const float fv[5] = {(float)j * (1.0f / 160.0f), (float)i * (1.0f / 160.0f),
                             img[0 * NPIX + px] * (1.0f / 3.0f),
                             img[1 * NPIX + px] * (1.0f / 3.0f),
                             img[2 * NPIX + px] * (1.0f / 3.0f)};
        const float env = __expf(-0.5f * (fv[0]*fv[0] + fv[1]*fv[1] + fv[2]*fv[2] +
                                          fv[3]*fv[3] + fv[4]*fv[4]));
        int m = 0;
        float p1 = env;
        #pragma unroll
        for (int e1 = 0; e1 <= 4; e1++) {
            float p2 = p1;
            #pragma unroll
            for (int e2 = 0; e2 <= 4 - e1; e2++) {
                float p3 = p2;
                #pragma unroll
                for (int e3 = 0; e3 <= 4 - e1 - e2; e3++) {
                    float p4 = p3;
                    #pragma unroll
                    for (int e4 = 0; e4 <= 4 - e1 - e2 - e3; e4++) {
                        float p5 = p4;
                        #pragma unroll
                        for (int e5 = 0; e5 <= 4 - e1 - e2 - e3 - e4; e5++) {
                            if ((unsigned)(m - c0) < 16u)
                                phi[(size_t)m * NPIX + px] = sg_sh[m] * p5;
                            ++m;
                            p5 *= fv[4];
                        }
                        p4 *= fv[3];
                    }
                    p3 *= fv[2];
                }
                p2 *= fv[1];
            }
            p1 *= fv[0];
        }
    }
}

// ---- K1: stage1 GEMM (LDS b128 dot, atomic M) || conv-x (unchanged) ----
__global__ __launch_bounds__(256) void k1_kernel(
    const float* __restrict__ s_pm, const float* __restrict__ s_cm,
    const float* __restrict__ phi, float* __restrict__ sx, float* __restrict__ M)
{
    __shared__ float smem[(NCH + MG) * LDSS];
    const int bid = blockIdx.x, tid = threadIdx.x;
    if (bid < NMG * 36) {
        const int g = bid / 36, chunk = bid % 36;
        const int m0 = g * MG;
        const int mcnt = (NMON - m0 < MG) ? (NMON - m0) : MG;
        float* s_sh = smem;
        float* p_sh = smem + NCH * LDSS;
        {
            const float4* sp = (const float4*)(s_pm + (size_t)(chunk * 256 + tid) * CP);
            #pragma unroll
            for (int v = 0; v < 6; v++) {
                const float4 t = sp[v];
                const int c = 4 * v;
                if (c < NCH)     s_sh[c * LDSS + tid] = t.x;
                if (c + 1 < NCH) s_sh[(c + 1) * LDSS + tid] = t.y;
                if (c + 2 < NCH) s_sh[(c + 2) * LDSS + tid] = t.z;
                if (c + 3 < NCH) s_sh[(c + 3) * LDSS + tid] = t.w;
            }
        }
        for (int idx = tid; idx < mcnt * 64; idx += 256) {
            const int mm = idx >> 6, p4 = idx & 63;
            const float4 t = *(const float4*)(phi + (size_t)(m0 + mm) * NPIX +
                                              chunk * 256 + p4 * 4);
            *(float4*)(p_sh + mm * LDSS + p4 * 4) = t;
        }
        __syncthreads();
        const int c = tid % NCH, msub = tid / NCH;
        if (msub < mcnt) {
            const float* sr = s_sh + c * LDSS;
            const float* pr = p_sh + msub * LDSS;
            float acc = 0.f;
            for (int p4 = 0; p4 < 64; p4++) {
                const float4 sv = *(const float4*)(sr + p4 * 4);
                const float4 pv = *(const float4*)(pr + p4 * 4);
                acc += pv.x * sv.x + pv.y * sv.y + pv.z * sv.z + pv.w * sv.w;
            }
            atomicAdd(&M[(m0 + msub) * NCH + c], acc);
        }
    } else {
        const int u2 = bid - NMG * 36;        // [0, 792)
        const int ch = u2 / 36, pc = u2 % 36;
        const int n = pc * 256 + tid, j = n % IMW;
        const float* row = s_cm + (size_t)ch * NPIX + (n - j);
        float a = GW[0] * row[j];
        #pragma unroll
        for (int d = 1; d <= RAD; d++) {
            const float l = (j - d >= 0) ? row[j - d] : 0.f;
            const float r = (j + d < IMW) ? row[j + d] : 0.f;
            a = fmaf(GW[d], l + r, a);
        }
        sx[(size_t)ch * NPIX + n] = a;
    }
}

// ---- K2: conv-y + stage2 + combine + softmax. 16 px/block, 576 blocks.
//      phi read directly from global in stage2 (L2-resident, coalesced);
//      u prefetched into q_sh at preamble. LDS ~24 KB. ----
__global__ __launch_bounds__(256) void k2_kernel(
    const float* __restrict__ sx, const float* __restrict__ phi,
    const float* __restrict__ M, float* __restrict__ Mnext,
    const float* __restrict__ u_pm,
    const float* __restrict__ sp_w, const float* __restrict__ sp_b,
    const float* __restrict__ bl_w, const float* __restrict__ bl_b,
    const float* __restrict__ comp_w, const float* __restrict__ comp_b,
    float* __restrict__ s_pm, float* __restrict__ s_cm,
    float* __restrict__ out, int write_out)
{
    __shared__ float Msh[NMON * CP];       // 12.1 KB
    __shared__ float cy_sh[K2PX * 25];     // conv-y (+norm slot)
    __shared__ float blv_sh[K2PX * 25];    // stage2 result
    __shared__ float mp_sh[K2PX * CP];
    __shared__ float q_sh[K2PX * CP];      // u (prefetch) -> q
    __shared__ float wsh[1386 + 63];
    const int tid = threadIdx.x;
    const int px0 = blockIdx.x * K2PX;
    const int i0 = px0 / IMW;              // block-uniform row (16 | 96)

    for (int idx = tid; idx < NMON * CP; idx += 256) {
        const int mm = idx / CP, c = idx % CP;
        Msh[idx] = (c < NCH) ? M[mm * NCH + c] : 0.f;
    }
    for (int idx = tid; idx < 441; idx += 256) {
        wsh[idx] = sp_w[idx]; wsh[441 + idx] = bl_w[idx]; wsh[882 + idx] = comp_w[idx];
    }
    if (tid < 21) {
        wsh[1323 + tid] = sp_b[tid]; wsh[1344 + tid] = bl_b[tid];
        wsh[1365 + tid] = comp_b[tid];
    }
    if (blockIdx.x < 11) {
        const int idx = blockIdx.x * 256 + tid;
        if (idx < 2772) Mnext[idx] = 0.f;
    }
    // u prefetch (contiguous 16*24 floats)
    for (int idx = tid; idx < K2PX * CP; idx += 256)
        q_sh[idx] = u_pm[(size_t)px0 * CP + idx];
    // conv-y: 22ch x 16px tasks
    for (int task = tid; task < NCH * K2PX; task += 256) {
        const int ch = task >> 4, p = task & 15;
        const int n = px0 + p;
        const float* plane = sx + (size_t)ch * NPIX;
        float a = GW[0] * plane[n];
        #pragma unroll
        for (int d = 1; d <= RAD; d++) {
            const float t = (i0 - d >= 0) ? plane[n - d * IMW] : 0.f;
            const float b = (i0 + d < IMH) ? plane[n + d * IMW] : 0.f;
            a = fmaf(GW[d], t + b, a);
        }
        cy_sh[p * 25 + ch] = a;
    }
    __syncthreads();

    // stage2: thread = (p = tid&15, 2-channel group cg = tid>>4); phi from global
    {
        const int p = tid & 15, c0 = (tid >> 4) * 2;
        if (c0 < NCH) {
            float a0 = 0.f, a1 = 0.f;
            const float* pcol = phi + px0 + p;
            for (int mm = 0; mm < NMON; mm++) {
                const float ph = pcol[(size_t)mm * NPIX];
                a0 = fmaf(ph, Msh[mm * CP + c0], a0);
                a1 = fmaf(ph, Msh[mm * CP + c0 + 1], a1);
            }
            blv_sh[p * 25 + c0] = a0;
            blv_sh[p * 25 + c0 + 1] = a1;
        }
    }
    __syncthreads();

    // matmul1: mp = sp_b + bl_b + (sp_w@cy)/cy_norm + (bl_w@blv)/blv_norm
    for (int t = tid; t < K2PX * NC; t += 256) {
        const int p = t & 15, o = t >> 4;
        const float* cyr = cy_sh + p * 25;
        const float* blr = blv_sh + p * 25;
        float dS = 0.f, dB = 0.f;
        #pragma unroll
        for (int c = 0; c < NC; c++) {
            dS = fmaf(wsh[o * NC + c], cyr[c], dS);
            dB = fmaf(wsh[441 + o * NC + c], blr[c], dB);
        }
        mp_sh[p * CP + o] = wsh[1323 + o] + wsh[1344 + o] +
                            dS / cyr[21] + dB / blr[21];
    }
    __syncthreads();

    // matmul2: q = u - (comp_w @ mp + comp_b)   (u already in q_sh)
    for (int t = tid; t < K2PX * NC; t += 256) {
        const int p = t & 15, o = t >> 4;
        const float* mpr = mp_sh + p * CP;
        float d = wsh[1365 + o];
        #pragma unroll
        for (int c = 0; c < NC; c++) d = fmaf(wsh[882 + o * NC + c], mpr[c], d);
        q_sh[p * CP + o] = q_sh[p * CP + o] - d;
    }
    __syncthreads();

    // softmax + writes, thread = pixel
    if (tid < K2PX) {
        const int n = px0 + tid;
        float q[NC];
        #pragma unroll
        for (int o = 0; o < NC; o++) q[o] = q_sh[tid * CP + o];
        float mx = q[0];
        #pragma unroll
        for (int o = 1; o < NC; o++) mx = fmaxf(mx, q[o]);
        float sum = 0.f;
        #pragma unroll
        for (int o = 0; o < NC; o++) { q[o] = __expf(q[o] - mx); sum += q[o]; }
        const float inv = 1.f / sum;
        #pragma unroll
        for (int o = 0; o < NC; o++) q[o] *= inv;

        float4* sp = (float4*)(s_pm + (size_t)n * CP);
        sp[0] = make_float4(q[0], q[1], q[2], q[3]);
        sp[1] = make_float4(q[4], q[5], q[6], q[7]);
        sp[2] = make_float4(q[8], q[9], q[10], q[11]);
        sp[3] = make_float4(q[12], q[13], q[14], q[15]);
        sp[4] = make_float4(q[16], q[17], q[18], q[19]);
        sp[5] = make_float4(q[20], 1.f, 0.f, 0.f);
        #pragma unroll
        for (int o = 0; o < NC; o++) s_cm[(size_t)o * NPIX + n] = q[o];
        s_cm[(size_t)21 * NPIX + n] = 1.f;
        if (write_out)
            #pragma unroll
            for (int o = 0; o < NC; o++) out[(size_t)o * NPIX + n] = q[o];
    }
}

extern "C" void kernel_launch(void* const* d_in, const int* in_sizes, int n_in,
                              void* d_out, int out_size, void* d_ws, size_t ws_size,
                              hipStream_t stream) {
    const float* img    = (const float*)d_in[0];
    const float* net_w  = (const float*)d_in[1];
    const float* net_b  = (const float*)d_in[2];
    const float* sp_w   = (const float*)d_in[3];
    const float* sp_b   = (const float*)d_in[4];
    const float* bl_w   = (const float*)d_in[5];
    const float* bl_b   = (const float*)d_in[6];
    const float* comp_w = (const float*)d_in[7];
    const float* comp_b = (const float*)d_in[8];

    float* u_pm = (float*)d_ws;                  // [NPIX][24]
    float* s_pm = u_pm + (size_t)NPIX * CP;      // [NPIX][24]
    float* s_cm = s_pm + (size_t)NPIX * CP;      // [22][NPIX]
    float* sx   = s_cm + (size_t)NCH * NPIX;     // [22][NPIX]
    float* phi  = sx + (size_t)NCH * NPIX;       // [126][NPIX]
    float* M    = phi + (size_t)NMON * NPIX;     // [2][MPAD]

    float* out = (float*)d_out;

    prep_kernel<<<dim3(36 + 288), dim3(256), 0, stream>>>(
        img, net_w, net_b, u_pm, s_pm, s_cm, phi, M);
    for (int it = 0; it < NITER; it++) {
        float* Mc = M + (it & 1) * MPAD;
        float* Mn = M + ((it + 1) & 1) * MPAD;
        k1_kernel<<<dim3(NMG * 36 + NCH * 36), dim3(256), 0, stream>>>(
            s_pm, s_cm, phi, sx, Mc);
        k2_kernel<<<dim3(NPIX / K2PX), dim3(256), 0, stream>>>(
            sx, phi, Mc, Mn, u_pm, sp_w, sp_b, bl_w, bl_b, comp_w, comp_b,
            s_pm, s_cm, out, it == NITER - 1 ? 1 : 0);
    }
}

// Round 9
// 205.648 us; speedup vs baseline: 2.0380x; 1.0062x over previous
//
#include <hip/hip_runtime.h>

#define NPIX 9216
#define IMH 96
#define IMW 96
#define NC 21
#define NCH 22          // 21 classes + norm channel
#define CP 24           // pixel-major channel pad; also M row pad
#define NMON 126        // monomials of degree <=4 in 5 vars
#define RAD 15
#define NITER 5
#define MG 11           // monomials per stage1 block
#define NMG 12          // ceil(126/11)
#define LDSS 260        // stage1 LDS pitch (float4-aligned, bank-spread)
#define MPAD 3072       // M buffer stride (>=126*24, float4-aligned)
#define K2PX 8          // k2 pixels per block (1152 blocks = 4.5/CU)

// spatial taps exp(-d^2/18), sigma=3
__constant__ float GW[16] = {
    1.0f, 0.945959f, 0.800737f, 0.606531f, 0.411112f, 0.249352f,
    0.135335f, 0.0657285f, 0.0285655f, 0.0111090f, 0.00386592f,
    0.00120386f, 0.000335463f, 8.36523e-05f, 1.86640e-05f, 3.72665e-06f};

// near-minimax deg-4 poly for exp(t) on [0, 1.0384] (all coeffs > 0)
__constant__ float d_bk[5] = {1.000000f, 0.998959f, 0.509936f, 0.139441f, 0.070024f};

// ---- P: two block roles, one dispatch (round-7, proven) ----
__global__ __launch_bounds__(256) void prep_kernel(
    const float* __restrict__ img, const float* __restrict__ net_w,
    const float* __restrict__ net_b,
    float* __restrict__ u_pm, float* __restrict__ s_pm, float* __restrict__ s_cm,
    float* __restrict__ phi, float* __restrict__ M0)
{
    __shared__ float wsh[567], bsh[21];
    __shared__ float sg_sh[NMON];
    const int tid = threadIdx.x;
    const int bid = blockIdx.x;

    if (bid < 36) {
        // ---- role A: unary conv + softmax + u/s + zero M0 ----
        for (int i2 = tid; i2 < 567; i2 += 256) wsh[i2] = net_w[i2];
        if (tid < 21) bsh[tid] = net_b[tid];
        __syncthreads();

        const int px = bid * 256 + tid;
        const int i = px / IMW, j = px % IMW;
        if (px < MPAD) M0[px] = 0.f;      // zero padded M buffer 0

        float acc[NC];
        #pragma unroll
        for (int o = 0; o < NC; o++) acc[o] = bsh[o];
        for (int ci = 0; ci < 3; ci++)
            for (int ky = 0; ky < 3; ky++)
                for (int kx = 0; kx < 3; kx++) {
                    const int ii = i + ky - 1, jj = j + kx - 1;
                    float v = 0.f;
                    if (ii >= 0 && ii < IMH && jj >= 0 && jj < IMW)
                        v = img[(ci * IMH + ii) * IMW + jj];
                    #pragma unroll
                    for (int o = 0; o < NC; o++)
                        acc[o] = fmaf(v, wsh[(ci * 3 + ky) * 3 + kx + o * 27], acc[o]);
                }
        {   // u then softmax
            float4* up = (float4*)(u_pm + (size_t)px * CP);
            up[0] = make_float4(acc[0], acc[1], acc[2], acc[3]);
            up[1] = make_float4(acc[4], acc[5], acc[6], acc[7]);
            up[2] = make_float4(acc[8], acc[9], acc[10], acc[11]);
            up[3] = make_float4(acc[12], acc[13], acc[14], acc[15]);
            up[4] = make_float4(acc[16], acc[17], acc[18], acc[19]);
            up[5] = make_float4(acc[20], 0.f, 0.f, 0.f);
        }
        float mx = acc[0];
        #pragma unroll
        for (int o = 1; o < NC; o++) mx = fmaxf(mx, acc[o]);
        float sum = 0.f;
        #pragma unroll
        for (int o = 0; o < NC; o++) { acc[o] = __expf(acc[o] - mx); sum += acc[o]; }
        const float inv = 1.f / sum;
        #pragma unroll
        for (int o = 0; o < NC; o++) acc[o] *= inv;
        {
            float4* sp = (float4*)(s_pm + (size_t)px * CP);
            sp[0] = make_float4(acc[0], acc[1], acc[2], acc[3]);
            sp[1] = make_float4(acc[4], acc[5], acc[6], acc[7]);
            sp[2] = make_float4(acc[8], acc[9], acc[10], acc[11]);
            sp[3] = make_float4(acc[12], acc[13], acc[14], acc[15]);
            sp[4] = make_float4(acc[16], acc[17], acc[18], acc[19]);
            sp[5] = make_float4(acc[20], 1.f, 0.f, 0.f);
        }
        #pragma unroll
        for (int o = 0; o < NC; o++) s_cm[(size_t)o * NPIX + px] = acc[o];
        s_cm[(size_t)21 * NPIX + px] = 1.f;
    } else {
        // ---- role B: phi, 8 threads/pixel, 16-monomial store window each ----
        for (int m = tid; m < NMON; m += 256) {
            int e1 = 0, e2 = 0, e3 = 0, e4 = 0, e5 = 0, cnt = 0;
            bool done = false;
            for (int a = 0; a <= 4 && !done; a++)
                for (int b2 = 0; b2 <= 4 - a && !done; b2++)
                    for (int c = 0; c <= 4 - a - b2 && !done; c++)
                        for (int d = 0; d <= 4 - a - b2 - c && !done; d++) {
                            const int rem = 4 - a - b2 - c - d;
                            if (m - cnt <= rem) {
                                e1 = a; e2 = b2; e3 = c; e4 = d; e5 = m - cnt;
                                done = true;
                            } else cnt += rem + 1;
                        }
            const float fact[5] = {1.f, 1.f, 2.f, 6.f, 24.f};
            const int k = e1 + e2 + e3 + e4 + e5;
            sg_sh[m] = sqrtf(d_bk[k] * fact[k] /
                             (fact[e1] * fact[e2] * fact[e3] * fact[e4] * fact[e5]));
        }
        __syncthreads();

        const int px = (bid - 36) * 32 + (tid & 31);
        const unsigned c0 = (tid >> 5) * 16;      // this thread's store window
        const int i = px / IMW, j = px % IMW;
        const float fv[5] = {(float)j * (1.0f / 160.0f), (float)i * (1.0f / 160.0f),
                             img[0 * NPIX + px] * (1.0f / 3.0f),
                             img[1 * NPIX + px] * (1.0f / 3.0f),
                             img[2 * NPIX + px] * (1.0f / 3.0f)};
        const float env = __expf(-0.5f * (fv[0]*fv[0] + fv[1]*fv[1] + fv[2]*fv[2] +
                                          fv[3]*fv[3] + fv[4]*fv[4]));
        int m = 0;
        float p1 = env;
        #pragma unroll
        for (int e1 = 0; e1 <= 4; e1++) {
            float p2 = p1;
            #pragma unroll
            for (int e2 = 0; e2 <= 4 - e1; e2++) {
                float p3 = p2;
                #pragma unroll
                for (int e3 = 0; e3 <= 4 - e1 - e2; e3++) {
                    float p4 = p3;
                    #pragma unroll
                    for (int e4 = 0; e4 <= 4 - e1 - e2 - e3; e4++) {
                        float p5 = p4;
                        #pragma unroll
                        for (int e5 = 0; e5 <= 4 - e1 - e2 - e3 - e4; e5++) {
                            if ((unsigned)(m - c0) < 16u)
                                phi[(size_t)m * NPIX + px] = sg_sh[m] * p5;
                            ++m;
                            p5 *= fv[4];
                        }
                        p4 *= fv[3];
                    }
                    p3 *= fv[2];
                }
                p2 *= fv[1];
            }
            p1 *= fv[0];
        }
    }
}

// ---- K1: stage1 GEMM (LDS b128 dot, atomic M, CP-padded rows) || conv-x ----
__global__ __launch_bounds__(256) void k1_kernel(
    const float* __restrict__ s_pm, const float* __restrict__ s_cm,
    const float* __restrict__ phi, float* __restrict__ sx, float* __restrict__ M)
{
    __shared__ float smem[(NCH + MG) * LDSS];
    const int bid = blockIdx.x, tid = threadIdx.x;
    if (bid < NMG * 36) {
        const int g = bid / 36, chunk = bid % 36;
        const int m0 = g * MG;
        const int mcnt = (NMON - m0 < MG) ? (NMON - m0) : MG;
        float* s_sh = smem;
        float* p_sh = smem + NCH * LDSS;
        {
            const float4* sp = (const float4*)(s_pm + (size_t)(chunk * 256 + tid) * CP);
            #pragma unroll
            for (int v = 0; v < 6; v++) {
                const float4 t = sp[v];
                const int c = 4 * v;
                if (c < NCH)     s_sh[c * LDSS + tid] = t.x;
                if (c + 1 < NCH) s_sh[(c + 1) * LDSS + tid] = t.y;
                if (c + 2 < NCH) s_sh[(c + 2) * LDSS + tid] = t.z;
                if (c + 3 < NCH) s_sh[(c + 3) * LDSS + tid] = t.w;
            }
        }
        for (int idx = tid; idx < mcnt * 64; idx += 256) {
            const int mm = idx >> 6, p4 = idx & 63;
            const float4 t = *(const float4*)(phi + (size_t)(m0 + mm) * NPIX +
                                              chunk * 256 + p4 * 4);
            *(float4*)(p_sh + mm * LDSS + p4 * 4) = t;
        }
        __syncthreads();
        const int c = tid % NCH, msub = tid / NCH;
        if (msub < mcnt) {
            const float* sr = s_sh + c * LDSS;
            const float* pr = p_sh + msub * LDSS;
            float acc = 0.f;
            for (int p4 = 0; p4 < 64; p4++) {
                const float4 sv = *(const float4*)(sr + p4 * 4);
                const float4 pv = *(const float4*)(pr + p4 * 4);
                acc += pv.x * sv.x + pv.y * sv.y + pv.z * sv.z + pv.w * sv.w;
            }
            atomicAdd(&M[(m0 + msub) * CP + c], acc);
        }
    } else {
        const int u2 = bid - NMG * 36;        // [0, 792)
        const int ch = u2 / 36, pc = u2 % 36;
        const int n = pc * 256 + tid, j = n % IMW;
        const float* row = s_cm + (size_t)ch * NPIX + (n - j);
        float a = GW[0] * row[j];
        #pragma unroll
        for (int d = 1; d <= RAD; d++) {
            const float l = (j - d >= 0) ? row[j - d] : 0.f;
            const float r = (j + d < IMW) ? row[j + d] : 0.f;
            a = fmaf(GW[d], l + r, a);
        }
        sx[(size_t)ch * NPIX + n] = a;
    }
}

// ---- K2: conv-y + stage2 + combine + softmax. 8 px/block, 1152 blocks.
//      M read as float4 [126][24]; phi direct from global; u prefetched. ----
__global__ __launch_bounds__(256) void k2_kernel(
    const float* __restrict__ sx, const float* __restrict__ phi,
    const float* __restrict__ M, float* __restrict__ Mnext,
    const float* __restrict__ u_pm,
    const float* __restrict__ sp_w, const float* __restrict__ sp_b,
    const float* __restrict__ bl_w, const float* __restrict__ bl_b,
    const float* __restrict__ comp_w, const float* __restrict__ comp_b,
    float* __restrict__ s_pm, float* __restrict__ s_cm,
    float* __restrict__ out, int write_out)
{
    __shared__ float Msh[NMON * CP];       // 12.1 KB, [126][24]
    __shared__ float cy_sh[K2PX * 25];     // conv-y (+norm slot)
    __shared__ float blv_sh[K2PX * 25];    // stage2 result
    __shared__ float mp_sh[K2PX * CP];
    __shared__ float q_sh[K2PX * CP];      // u (prefetch) -> q
    __shared__ float wsh[1386 + 63];
    const int tid = threadIdx.x;
    const int px0 = blockIdx.x * K2PX;
    const int i0 = px0 / IMW;              // block-uniform row (8 | 96)

    // Msh: vectorized copy of padded M (pad cols are zero-initialized, unwritten)
    {
        float4* M4 = (float4*)Msh;
        const float4* Mc4 = (const float4*)M;
        for (int idx = tid; idx < NMON * CP / 4; idx += 256) M4[idx] = Mc4[idx];
    }
    for (int idx = tid; idx < 441; idx += 256) {
        wsh[idx] = sp_w[idx]; wsh[441 + idx] = bl_w[idx]; wsh[882 + idx] = comp_w[idx];
    }
    if (tid < 21) {
        wsh[1323 + tid] = sp_b[tid]; wsh[1344 + tid] = bl_b[tid];
        wsh[1365 + tid] = comp_b[tid];
    }
    if (blockIdx.x < 12) {
        const int idx = blockIdx.x * 256 + tid;
        if (idx < MPAD) Mnext[idx] = 0.f;
    }
    // u prefetch (contiguous 8*24 floats)
    for (int idx = tid; idx < K2PX * CP; idx += 256)
        q_sh[idx] = u_pm[(size_t)px0 * CP + idx];
    // conv-y: 22ch x 8px tasks (single round)
    if (tid < NCH * K2PX) {
        const int ch = tid >> 3, p = tid & 7;
        const int n = px0 + p;
        const float* plane = sx + (size_t)ch * NPIX;
        float a = GW[0] * plane[n];
        #pragma unroll
        for (int d = 1; d <= RAD; d++) {
            const float t = (i0 - d >= 0) ? plane[n - d * IMW] : 0.f;
            const float b = (i0 + d < IMH) ? plane[n + d * IMW] : 0.f;
            a = fmaf(GW[d], t + b, a);
        }
        cy_sh[p * 25 + ch] = a;
    }
    __syncthreads();

    // stage2: thread = (p = tid&7, ch = tid>>3); 1 channel each; phi from global
    {
        const int p = tid & 7, ch = tid >> 3;
        if (ch < NCH) {
            float a0 = 0.f;
            const float* pcol = phi + px0 + p;
            for (int mm = 0; mm < NMON; mm++)
                a0 = fmaf(pcol[(size_t)mm * NPIX], Msh[mm * CP + ch], a0);
            blv_sh[p * 25 + ch] = a0;
        }
    }
    __syncthreads();

    // matmul1: mp = sp_b + bl_b + (sp_w@cy)/cy_norm + (bl_w@blv)/blv_norm
    if (tid < K2PX * NC) {
        const int p = tid & 7, o = tid >> 3;
        const float* cyr = cy_sh + p * 25;
        const float* blr = blv_sh + p * 25;
        float dS = 0.f, dB = 0.f;
        #pragma unroll
        for (int c = 0; c < NC; c++) {
            dS = fmaf(wsh[o * NC + c], cyr[c], dS);
            dB = fmaf(wsh[441 + o * NC + c], blr[c], dB);
        }
        mp_sh[p * CP + o] = wsh[1323 + o] + wsh[1344 + o] +
                            dS / cyr[21] + dB / blr[21];
    }
    __syncthreads();

    // matmul2: q = u - (comp_w @ mp + comp_b)   (u already in q_sh)
    if (tid < K2PX * NC) {
        const int p = tid & 7, o = tid >> 3;
        const float* mpr = mp_sh + p * CP;
        float d = wsh[1365 + o];
        #pragma unroll
        for (int c = 0; c < NC; c++) d = fmaf(wsh[882 + o * NC + c], mpr[c], d);
        q_sh[p * CP + o] = q_sh[p * CP + o] - d;
    }
    __syncthreads();

    // softmax + writes, thread = pixel
    if (tid < K2PX) {
        const int n = px0 + tid;
        float q[NC];
        #pragma unroll
        for (int o = 0; o < NC; o++) q[o] = q_sh[tid * CP + o];
        float mx = q[0];
        #pragma unroll
        for (int o = 1; o < NC; o++) mx = fmaxf(mx, q[o]);
        float sum = 0.f;
        #pragma unroll
        for (int o = 0; o < NC; o++) { q[o] = __expf(q[o] - mx); sum += q[o]; }
        const float inv = 1.f / sum;
        #pragma unroll
        for (int o = 0; o < NC; o++) q[o] *= inv;

        float4* sp = (float4*)(s_pm + (size_t)n * CP);
        sp[0] = make_float4(q[0], q[1], q[2], q[3]);
        sp[1] = make_float4(q[4], q[5], q[6], q[7]);
        sp[2] = make_float4(q[8], q[9], q[10], q[11]);
        sp[3] = make_float4(q[12], q[13], q[14], q[15]);
        sp[4] = make_float4(q[16], q[17], q[18], q[19]);
        sp[5] = make_float4(q[20], 1.f, 0.f, 0.f);
        #pragma unroll
        for (int o = 0; o < NC; o++) s_cm[(size_t)o * NPIX + n] = q[o];
        s_cm[(size_t)21 * NPIX + n] = 1.f;
        if (write_out)
            #pragma unroll
            for (int o = 0; o < NC; o++) out[(size_t)o * NPIX + n] = q[o];
    }
}

extern "C" void kernel_launch(void* const* d_in, const int* in_sizes, int n_in,
                              void* d_out, int out_size, void* d_ws, size_t ws_size,
                              hipStream_t stream) {
    const float* img    = (const float*)d_in[0];
    const float* net_w  = (const float*)d_in[1];
    const float* net_b  = (const float*)d_in[2];
    const float* sp_w   = (const float*)d_in[3];
    const float* sp_b   = (const float*)d_in[4];
    const float* bl_w   = (const float*)d_in[5];
    const float* bl_b   = (const float*)d_in[6];
    const float* comp_w = (const float*)d_in[7];
    const float* comp_b = (const float*)d_in[8];

    float* u_pm = (float*)d_ws;                  // [NPIX][24]
    float* s_pm = u_pm + (size_t)NPIX * CP;      // [NPIX][24]
    float* s_cm = s_pm + (size_t)NPIX * CP;      // [22][NPIX]
    float* sx   = s_cm + (size_t)NCH * NPIX;     // [22][NPIX]
    float* phi  = sx + (size_t)NCH * NPIX;       // [126][NPIX]
    float* M    = phi + (size_t)NMON * NPIX;     // [2][MPAD], rows CP-padded

    float* out = (float*)d_out;

    prep_kernel<<<dim3(36 + 288), dim3(256), 0, stream>>>(
        img, net_w, net_b, u_pm, s_pm, s_cm, phi, M);
    for (int it = 0; it < NITER; it++) {
        float* Mc = M + (it & 1) * MPAD;
        float* Mn = M + ((it + 1) & 1) * MPAD;
        k1_kernel<<<dim3(NMG * 36 + NCH * 36), dim3(256), 0, stream>>>(
            s_pm, s_cm, phi, sx, Mc);
        k2_kernel<<<dim3(NPIX / K2PX), dim3(256), 0, stream>>>(
            sx, phi, Mc, Mn, u_pm, sp_w, sp_b, bl_w, bl_b, comp_w, comp_b,
            s_pm, s_cm, out, it == NITER - 1 ? 1 : 0);
    }
}